// Round 1
// baseline (2652.473 us; speedup 1.0000x reference)
//
#include <hip/hip_runtime.h>
#include <hip/hip_bf16.h>
#include <math.h>

#define B_  2
#define T_  2048
#define D_  1024
#define H_  16
#define HD_ 64

// ---------------------------------------------------------------------------
// C[N,M] = A[N,K] @ W[K,M] + bias[M]    (fp32, LDS-tiled, 4x4 micro-tile)
// BM=64 rows, BN=64 cols, BK=16. 256 threads.
// As stored k-major (As[k][row]) so compute reads are float4.
// ---------------------------------------------------------------------------
template<int BM, int BN, int BK>
__global__ __launch_bounds__(256)
void gemm_bias_kernel(const float* __restrict__ A, const float* __restrict__ W,
                      const float* __restrict__ bias, float* __restrict__ C,
                      int N, int K, int M)
{
    __shared__ __align__(16) float As[BK][BM + 4];   // stride 68 keeps 16B align
    __shared__ __align__(16) float Bs[BK][BN + 4];

    const int tid = threadIdx.x;
    const int tx = tid & 15;          // output col quad
    const int ty = tid >> 4;          // output row quad
    const int m0 = blockIdx.x * BN;
    const int n0 = blockIdx.y * BM;

    const int ar  = tid >> 2;         // A load: row within tile (0..63)
    const int akq = tid & 3;          // A load: k-quad (0..3)
    const int wk  = tid >> 4;         // W load: k within tile (0..15)
    const int wmq = tid & 15;         // W load: m-quad (0..15)

    float acc[4][4] = {};

    for (int k0 = 0; k0 < K; k0 += BK) {
        float4 av = *(const float4*)&A[(size_t)(n0 + ar) * K + k0 + akq * 4];
        float4 wv = *(const float4*)&W[(size_t)(k0 + wk) * M + m0 + wmq * 4];
        As[akq * 4 + 0][ar] = av.x;
        As[akq * 4 + 1][ar] = av.y;
        As[akq * 4 + 2][ar] = av.z;
        As[akq * 4 + 3][ar] = av.w;
        *(float4*)&Bs[wk][wmq * 4] = wv;
        __syncthreads();
        #pragma unroll
        for (int kk = 0; kk < BK; kk++) {
            float4 a = *(const float4*)&As[kk][ty * 4];
            float4 b = *(const float4*)&Bs[kk][tx * 4];
            acc[0][0] += a.x * b.x; acc[0][1] += a.x * b.y; acc[0][2] += a.x * b.z; acc[0][3] += a.x * b.w;
            acc[1][0] += a.y * b.x; acc[1][1] += a.y * b.y; acc[1][2] += a.y * b.z; acc[1][3] += a.y * b.w;
            acc[2][0] += a.z * b.x; acc[2][1] += a.z * b.y; acc[2][2] += a.z * b.z; acc[2][3] += a.z * b.w;
            acc[3][0] += a.w * b.x; acc[3][1] += a.w * b.y; acc[3][2] += a.w * b.z; acc[3][3] += a.w * b.w;
        }
        __syncthreads();
    }

    float4 bv = *(const float4*)&bias[m0 + tx * 4];
    #pragma unroll
    for (int i = 0; i < 4; i++) {
        float4 o;
        o.x = acc[i][0] + bv.x;
        o.y = acc[i][1] + bv.y;
        o.z = acc[i][2] + bv.z;
        o.w = acc[i][3] + bv.w;
        *(float4*)&C[(size_t)(n0 + ty * 4 + i) * M + m0 + tx * 4] = o;
    }
}

// ---------------------------------------------------------------------------
// Flash-style causal attention. One workgroup per (b, h, 64-query tile).
// qkv layout: [(b*T + t)*3 + s]*D + h*HD + d   (s: 0=q,1=k,2=v)
// y layout:   [b*T + t]*D + h*HD + d
// 256 threads: thread owns q-row r = tid>>2 and d-segment seg = tid&3 (16 d).
// ---------------------------------------------------------------------------
__global__ __launch_bounds__(256)
void attn_kernel(const float* __restrict__ qkv, float* __restrict__ y)
{
    const int qb = blockIdx.x;   // query tile (0..31)
    const int h  = blockIdx.y;
    const int b  = blockIdx.z;

    __shared__ __align__(16) float Qs[64][68];
    __shared__ __align__(16) float Ks[64][68];
    __shared__ __align__(16) float Vs[64][68];
    __shared__ __align__(16) float Ss[64][68];
    __shared__ float alphas[64];
    __shared__ float lrow[64];

    const int tid = threadIdx.x;
    const int r   = tid >> 2;    // q row (0..63)
    const int seg = tid & 3;     // 16-wide d/k segment

    // ---- load Q tile (64 rows x 64 d) ----
    #pragma unroll
    for (int i = 0; i < 4; i++) {
        int f  = tid + i * 256;      // float4 index 0..1023
        int rr = f >> 4, c4 = f & 15;
        size_t g = ((size_t)((b * T_ + qb * 64 + rr) * 3 + 0)) * D_ + h * HD_ + c4 * 4;
        *(float4*)&Qs[rr][c4 * 4] = *(const float4*)&qkv[g];
    }
    __syncthreads();

    float4 qreg[16];
    #pragma unroll
    for (int i = 0; i < 16; i++) qreg[i] = *(const float4*)&Qs[r][i * 4];

    float4 O4[4];
    #pragma unroll
    for (int i = 0; i < 4; i++) O4[i] = make_float4(0.f, 0.f, 0.f, 0.f);
    float m = -INFINITY, l = 0.f;

    for (int kb = 0; kb <= qb; kb++) {
        __syncthreads();   // previous iteration's PV reads done
        #pragma unroll
        for (int i = 0; i < 4; i++) {
            int f  = tid + i * 256;
            int rr = f >> 4, c4 = f & 15;
            size_t gk = ((size_t)((b * T_ + kb * 64 + rr) * 3 + 1)) * D_ + h * HD_ + c4 * 4;
            size_t gv = ((size_t)((b * T_ + kb * 64 + rr) * 3 + 2)) * D_ + h * HD_ + c4 * 4;
            *(float4*)&Ks[rr][c4 * 4] = *(const float4*)&qkv[gk];
            *(float4*)&Vs[rr][c4 * 4] = *(const float4*)&qkv[gv];
        }
        __syncthreads();

        // ---- S = scale * Q K^T  (thread: row r, keys seg*16..seg*16+15) ----
        #pragma unroll
        for (int j = 0; j < 16; j++) {
            int kk = seg * 16 + j;
            float4 acc = make_float4(0.f, 0.f, 0.f, 0.f);
            #pragma unroll
            for (int dq = 0; dq < 16; dq++) {
                float4 kv = *(const float4*)&Ks[kk][dq * 4];
                acc.x += qreg[dq].x * kv.x;
                acc.y += qreg[dq].y * kv.y;
                acc.z += qreg[dq].z * kv.z;
                acc.w += qreg[dq].w * kv.w;
            }
            float s = (acc.x + acc.y + acc.z + acc.w) * 0.125f;
            if (kb == qb && kk > r) s = -INFINITY;   // causal mask on diagonal tile
            Ss[r][kk] = s;
        }
        __syncthreads();

        // ---- online softmax, one lane per row ----
        if (tid < 64) {
            float rm = -INFINITY;
            for (int k = 0; k < 64; k++) rm = fmaxf(rm, Ss[tid][k]);
            float nm    = fmaxf(m, rm);
            float alpha = __expf(m - nm);
            float sum   = 0.f;
            for (int k = 0; k < 64; k++) {
                float p = __expf(Ss[tid][k] - nm);
                sum += p;
                Ss[tid][k] = p;
            }
            l = l * alpha + sum;
            m = nm;
            alphas[tid] = alpha;
        }
        __syncthreads();

        // ---- O = O*alpha + P V ----
        float alpha = alphas[r];
        #pragma unroll
        for (int dq = 0; dq < 4; dq++) {
            O4[dq].x *= alpha; O4[dq].y *= alpha; O4[dq].z *= alpha; O4[dq].w *= alpha;
        }
        #pragma unroll 8
        for (int kk = 0; kk < 64; kk++) {
            float p = Ss[r][kk];
            #pragma unroll
            for (int dq = 0; dq < 4; dq++) {
                float4 vv = *(const float4*)&Vs[kk][seg * 16 + dq * 4];
                O4[dq].x += p * vv.x;
                O4[dq].y += p * vv.y;
                O4[dq].z += p * vv.z;
                O4[dq].w += p * vv.w;
            }
        }
    }

    if (tid < 64) lrow[tid] = l;
    __syncthreads();
    float linv = 1.0f / lrow[r];

    size_t gy = (size_t)(b * T_ + qb * 64 + r) * D_ + h * HD_ + seg * 16;
    #pragma unroll
    for (int dq = 0; dq < 4; dq++) {
        float4 o;
        o.x = O4[dq].x * linv;
        o.y = O4[dq].y * linv;
        o.z = O4[dq].z * linv;
        o.w = O4[dq].w * linv;
        *(float4*)&y[gy + dq * 4] = o;
    }
}

// ---------------------------------------------------------------------------
extern "C" void kernel_launch(void* const* d_in, const int* in_sizes, int n_in,
                              void* d_out, int out_size, void* d_ws, size_t ws_size,
                              hipStream_t stream)
{
    const float* x    = (const float*)d_in[0];
    const float* Wqkv = (const float*)d_in[1];
    const float* bqkv = (const float*)d_in[2];
    const float* Wout = (const float*)d_in[3];
    const float* bout = (const float*)d_in[4];
    float* out = (float*)d_out;

    float* qkv = (float*)d_ws;                                        // 4096*3072 fp32 = 50.3 MB
    float* y   = (float*)((char*)d_ws + (size_t)(B_*T_) * 3 * D_ * sizeof(float)); // 16.8 MB

    // 1) qkv = x @ Wqkv + bqkv     [4096,1024]x[1024,3072]
    gemm_bias_kernel<64, 64, 16><<<dim3(3 * D_ / 64, (B_ * T_) / 64), 256, 0, stream>>>(
        x, Wqkv, bqkv, qkv, B_ * T_, D_, 3 * D_);

    // 2) flash causal attention -> y [4096,1024]
    attn_kernel<<<dim3(T_ / 64, H_, B_), 256, 0, stream>>>(qkv, y);

    // 3) out = y @ Wout + bout     [4096,1024]x[1024,1024]
    gemm_bias_kernel<64, 64, 16><<<dim3(D_ / 64, (B_ * T_) / 64), 256, 0, stream>>>(
        y, Wout, bout, out, B_ * T_, D_, D_);
}

// Round 2
// 664.409 us; speedup vs baseline: 3.9922x; 3.9922x over previous
//
#include <hip/hip_runtime.h>
#include <hip/hip_bf16.h>
#include <math.h>

#define B_  2
#define T_  2048
#define D_  1024
#define H_  16
#define HD_ 64
#define LSTR 72   // LDS row stride in ushorts: 144B = 16B-aligned, non-pow2 banks

typedef __attribute__((ext_vector_type(8))) short short8;
typedef __attribute__((ext_vector_type(4))) float f32x4;

__device__ __forceinline__ ushort f2bf(float x) {
    unsigned u = __builtin_bit_cast(unsigned, x);
    return (ushort)((u + 0x7FFFu + ((u >> 16) & 1u)) >> 16);  // RTNE
}

// ---------------------------------------------------------------------------
// fp32 GEMM template: C[N,M] = A[N,K] @ W[K,M] + bias[M]   (unchanged baseline)
// ---------------------------------------------------------------------------
template<int BM, int BN, int BK>
__global__ __launch_bounds__(256)
void gemm_bias_kernel(const float* __restrict__ A, const float* __restrict__ W,
                      const float* __restrict__ bias, float* __restrict__ C,
                      int N, int K, int M)
{
    __shared__ __align__(16) float As[BK][BM + 4];
    __shared__ __align__(16) float Bs[BK][BN + 4];

    const int tid = threadIdx.x;
    const int tx = tid & 15;
    const int ty = tid >> 4;
    const int m0 = blockIdx.x * BN;
    const int n0 = blockIdx.y * BM;

    const int ar  = tid >> 2;
    const int akq = tid & 3;
    const int wk  = tid >> 4;
    const int wmq = tid & 15;

    float acc[4][4] = {};

    for (int k0 = 0; k0 < K; k0 += BK) {
        float4 av = *(const float4*)&A[(size_t)(n0 + ar) * K + k0 + akq * 4];
        float4 wv = *(const float4*)&W[(size_t)(k0 + wk) * M + m0 + wmq * 4];
        As[akq * 4 + 0][ar] = av.x;
        As[akq * 4 + 1][ar] = av.y;
        As[akq * 4 + 2][ar] = av.z;
        As[akq * 4 + 3][ar] = av.w;
        *(float4*)&Bs[wk][wmq * 4] = wv;
        __syncthreads();
        #pragma unroll
        for (int kk = 0; kk < BK; kk++) {
            float4 a = *(const float4*)&As[kk][ty * 4];
            float4 b = *(const float4*)&Bs[kk][tx * 4];
            acc[0][0] += a.x * b.x; acc[0][1] += a.x * b.y; acc[0][2] += a.x * b.z; acc[0][3] += a.x * b.w;
            acc[1][0] += a.y * b.x; acc[1][1] += a.y * b.y; acc[1][2] += a.y * b.z; acc[1][3] += a.y * b.w;
            acc[2][0] += a.z * b.x; acc[2][1] += a.z * b.y; acc[2][2] += a.z * b.z; acc[2][3] += a.z * b.w;
            acc[3][0] += a.w * b.x; acc[3][1] += a.w * b.y; acc[3][2] += a.w * b.z; acc[3][3] += a.w * b.w;
        }
        __syncthreads();
    }

    float4 bv = *(const float4*)&bias[m0 + tx * 4];
    #pragma unroll
    for (int i = 0; i < 4; i++) {
        float4 o;
        o.x = acc[i][0] + bv.x;
        o.y = acc[i][1] + bv.y;
        o.z = acc[i][2] + bv.z;
        o.w = acc[i][3] + bv.w;
        *(float4*)&C[(size_t)(n0 + ty * 4 + i) * M + m0 + tx * 4] = o;
    }
}

// ---------------------------------------------------------------------------
// QKV GEMM: same fp32 compute, epilogue writes bf16 Q,K row-major [b,h,t,d]
// and V transposed [b,h,d,t] so attention MFMA fragments are k-contiguous.
// ---------------------------------------------------------------------------
__global__ __launch_bounds__(256)
void gemm_qkv_kernel(const float* __restrict__ A, const float* __restrict__ W,
                     const float* __restrict__ bias,
                     ushort* __restrict__ Qg, ushort* __restrict__ Kg,
                     ushort* __restrict__ Vtg)
{
    const int K = D_, M = 3 * D_;
    __shared__ __align__(16) float As[16][68];
    __shared__ __align__(16) float Bs[16][68];

    const int tid = threadIdx.x;
    const int tx = tid & 15;
    const int ty = tid >> 4;
    const int m0 = blockIdx.x * 64;
    const int n0 = blockIdx.y * 64;

    const int ar  = tid >> 2;
    const int akq = tid & 3;
    const int wk  = tid >> 4;
    const int wmq = tid & 15;

    float acc[4][4] = {};

    for (int k0 = 0; k0 < K; k0 += 16) {
        float4 av = *(const float4*)&A[(size_t)(n0 + ar) * K + k0 + akq * 4];
        float4 wv = *(const float4*)&W[(size_t)(k0 + wk) * M + m0 + wmq * 4];
        As[akq * 4 + 0][ar] = av.x;
        As[akq * 4 + 1][ar] = av.y;
        As[akq * 4 + 2][ar] = av.z;
        As[akq * 4 + 3][ar] = av.w;
        *(float4*)&Bs[wk][wmq * 4] = wv;
        __syncthreads();
        #pragma unroll
        for (int kk = 0; kk < 16; kk++) {
            float4 a = *(const float4*)&As[kk][ty * 4];
            float4 b = *(const float4*)&Bs[kk][tx * 4];
            acc[0][0] += a.x * b.x; acc[0][1] += a.x * b.y; acc[0][2] += a.x * b.z; acc[0][3] += a.x * b.w;
            acc[1][0] += a.y * b.x; acc[1][1] += a.y * b.y; acc[1][2] += a.y * b.z; acc[1][3] += a.y * b.w;
            acc[2][0] += a.z * b.x; acc[2][1] += a.z * b.y; acc[2][2] += a.z * b.z; acc[2][3] += a.z * b.w;
            acc[3][0] += a.w * b.x; acc[3][1] += a.w * b.y; acc[3][2] += a.w * b.z; acc[3][3] += a.w * b.w;
        }
        __syncthreads();
    }

    float4 bv = *(const float4*)&bias[m0 + tx * 4];
    float bvj[4] = {bv.x, bv.y, bv.z, bv.w};
    const int s  = m0 >> 10;           // 0=q, 1=k, 2=v
    const int h  = (m0 & 1023) >> 6;   // head
    const int b  = n0 >> 11;           // batch
    const int t0 = n0 & 2047;          // token base

    if (s < 2) {
        ushort* dst = (s == 0 ? Qg : Kg) + ((size_t)(b * H_ + h) * T_ + t0) * HD_;
        #pragma unroll
        for (int i = 0; i < 4; i++) {
            ushort4 o;
            o.x = f2bf(acc[i][0] + bvj[0]);
            o.y = f2bf(acc[i][1] + bvj[1]);
            o.z = f2bf(acc[i][2] + bvj[2]);
            o.w = f2bf(acc[i][3] + bvj[3]);
            *(ushort4*)&dst[(size_t)(ty * 4 + i) * HD_ + tx * 4] = o;
        }
    } else {
        ushort* dst = Vtg + (size_t)(b * H_ + h) * HD_ * T_;
        #pragma unroll
        for (int j = 0; j < 4; j++) {
            ushort4 o;
            o.x = f2bf(acc[0][j] + bvj[j]);
            o.y = f2bf(acc[1][j] + bvj[j]);
            o.z = f2bf(acc[2][j] + bvj[j]);
            o.w = f2bf(acc[3][j] + bvj[j]);
            *(ushort4*)&dst[(size_t)(tx * 4 + j) * T_ + t0 + ty * 4] = o;
        }
    }
}

// ---------------------------------------------------------------------------
// MFMA bf16 flash attention. Block = 4 waves = one 64-row Q tile per (b,h).
// Wave w owns Q rows [w*16, w*16+16). 16x16x32 mfma; HD=64 => 2 k-steps.
// S/O C/D layout: row=(lane>>4)*4+reg, col=lane&15. A-layout: row=lane&15,
// k=(lane>>4)*8+j  => P needs an LDS round trip (wave-private, no barrier).
// ---------------------------------------------------------------------------
__global__ __launch_bounds__(256)
void attn_mfma(const ushort* __restrict__ Qg, const ushort* __restrict__ Kg,
               const ushort* __restrict__ Vtg, float* __restrict__ y)
{
    const int qb = blockIdx.x, h = blockIdx.y, b = blockIdx.z;
    const int tid = threadIdx.x;
    const int w  = tid >> 6;
    const int L  = tid & 63;
    const int lt = L & 15;     // fragment row/col
    const int lq = L >> 4;     // quad

    __shared__ __align__(16) ushort Ks [64 * LSTR];
    __shared__ __align__(16) ushort Vts[64 * LSTR];
    __shared__ __align__(16) ushort Ps [4][16 * LSTR];

    const size_t bh = (size_t)(b * H_ + h);
    const ushort* Qbase  = Qg  + bh * T_ * HD_;
    const ushort* Kbase  = Kg  + bh * T_ * HD_;
    const ushort* Vtbase = Vtg + bh * HD_ * T_;

    // Q fragments straight from global (wave's 16 rows)
    short8 qf[2];
    {
        const int row = qb * 64 + w * 16 + lt;
        qf[0] = *(const short8*)(Qbase + (size_t)row * HD_ + lq * 8);
        qf[1] = *(const short8*)(Qbase + (size_t)row * HD_ + 32 + lq * 8);
    }

    f32x4 acc_o[4] = {};           // 4 d-tiles, rows via reg
    float m_r[4], l_r[4];
    #pragma unroll
    for (int r = 0; r < 4; r++) { m_r[r] = -3.0e38f; l_r[r] = 0.f; }

    const float cscale = 0.125f * 1.4426950408889634f;  // scale * log2(e)
    const int tK = tid >> 3;   // 0..31 (row for staging)
    const int cK = tid & 7;    // 16B chunk within 128B row

    for (int kb = 0; kb <= qb; kb++) {
        __syncthreads();       // prior iteration's LDS reads done
        #pragma unroll
        for (int rr = 0; rr < 2; rr++) {
            const int row = tK + 32 * rr;
            *(short8*)&Ks [row * LSTR + cK * 8] =
                *(const short8*)(Kbase + (size_t)(kb * 64 + row) * HD_ + cK * 8);
            *(short8*)&Vts[row * LSTR + cK * 8] =
                *(const short8*)(Vtbase + (size_t)row * T_ + kb * 64 + cK * 8);
        }
        __syncthreads();

        // ---- S = Q K^T (4 n-tiles x 2 k-steps) ----
        f32x4 s_acc[4];
        #pragma unroll
        for (int nt = 0; nt < 4; nt++) {
            short8 kf0 = *(const short8*)&Ks[(nt * 16 + lt) * LSTR + lq * 8];
            short8 kf1 = *(const short8*)&Ks[(nt * 16 + lt) * LSTR + 32 + lq * 8];
            f32x4 c = {};
            c = __builtin_amdgcn_mfma_f32_16x16x32_bf16(qf[0], kf0, c, 0, 0, 0);
            c = __builtin_amdgcn_mfma_f32_16x16x32_bf16(qf[1], kf1, c, 0, 0, 0);
            s_acc[nt] = c;
        }

        // scale to base-2 domain + causal mask (diagonal tile only)
        #pragma unroll
        for (int nt = 0; nt < 4; nt++)
            #pragma unroll
            for (int r = 0; r < 4; r++)
                s_acc[nt][r] *= cscale;
        if (kb == qb) {
            #pragma unroll
            for (int nt = 0; nt < 4; nt++)
                #pragma unroll
                for (int r = 0; r < 4; r++)
                    if (nt * 16 + lt > w * 16 + lq * 4 + r) s_acc[nt][r] = -3.0e38f;
        }

        // ---- online softmax in registers (rows: 16-lane shfl groups) ----
        float alpha[4];
        #pragma unroll
        for (int r = 0; r < 4; r++) {
            float v = fmaxf(fmaxf(s_acc[0][r], s_acc[1][r]),
                            fmaxf(s_acc[2][r], s_acc[3][r]));
            #pragma unroll
            for (int off = 1; off < 16; off <<= 1)
                v = fmaxf(v, __shfl_xor(v, off, 64));
            float nm = fmaxf(m_r[r], v);
            alpha[r] = exp2f(m_r[r] - nm);
            float ssum = 0.f;
            #pragma unroll
            for (int nt = 0; nt < 4; nt++) {
                float p = exp2f(s_acc[nt][r] - nm);
                s_acc[nt][r] = p;
                ssum += p;
            }
            #pragma unroll
            for (int off = 1; off < 16; off <<= 1)
                ssum += __shfl_xor(ssum, off, 64);
            l_r[r] = l_r[r] * alpha[r] + ssum;
            m_r[r] = nm;
        }

        #pragma unroll
        for (int dt = 0; dt < 4; dt++)
            #pragma unroll
            for (int r = 0; r < 4; r++)
                acc_o[dt][r] *= alpha[r];

        // ---- P: C/D layout -> LDS (wave-private) -> A layout ----
        #pragma unroll
        for (int nt = 0; nt < 4; nt++)
            #pragma unroll
            for (int r = 0; r < 4; r++)
                Ps[w][(lq * 4 + r) * LSTR + nt * 16 + lt] = f2bf(s_acc[nt][r]);

        short8 pf0 = *(const short8*)&Ps[w][lt * LSTR + lq * 8];
        short8 pf1 = *(const short8*)&Ps[w][lt * LSTR + 32 + lq * 8];

        // ---- O += P V ----
        #pragma unroll
        for (int dt = 0; dt < 4; dt++) {
            short8 vf0 = *(const short8*)&Vts[(dt * 16 + lt) * LSTR + lq * 8];
            short8 vf1 = *(const short8*)&Vts[(dt * 16 + lt) * LSTR + 32 + lq * 8];
            acc_o[dt] = __builtin_amdgcn_mfma_f32_16x16x32_bf16(pf0, vf0, acc_o[dt], 0, 0, 0);
            acc_o[dt] = __builtin_amdgcn_mfma_f32_16x16x32_bf16(pf1, vf1, acc_o[dt], 0, 0, 0);
        }
    }

    // ---- epilogue: normalize, write fp32 y[b*T+t][h*64+d] ----
    float inv_l[4];
    #pragma unroll
    for (int r = 0; r < 4; r++) inv_l[r] = 1.0f / l_r[r];

    float* ybase = y + (size_t)(b * T_ + qb * 64 + w * 16) * D_ + h * HD_;
    #pragma unroll
    for (int r = 0; r < 4; r++)
        #pragma unroll
        for (int dt = 0; dt < 4; dt++)
            ybase[(size_t)(lq * 4 + r) * D_ + dt * 16 + lt] = acc_o[dt][r] * inv_l[r];
}

// ---------------------------------------------------------------------------
extern "C" void kernel_launch(void* const* d_in, const int* in_sizes, int n_in,
                              void* d_out, int out_size, void* d_ws, size_t ws_size,
                              hipStream_t stream)
{
    const float* x    = (const float*)d_in[0];
    const float* Wqkv = (const float*)d_in[1];
    const float* bqkv = (const float*)d_in[2];
    const float* Wout = (const float*)d_in[3];
    const float* bout = (const float*)d_in[4];
    float* out = (float*)d_out;

    char* ws = (char*)d_ws;
    const size_t qkv_elems = (size_t)B_ * H_ * T_ * HD_;      // 4 Mi elems
    ushort* Qg  = (ushort*)ws;                                 // 8 MB
    ushort* Kg  = (ushort*)(ws + qkv_elems * 2);               // 8 MB
    ushort* Vtg = (ushort*)(ws + qkv_elems * 4);               // 8 MB
    float*  y   = (float*) (ws + qkv_elems * 6);               // 16.8 MB

    // 1) qkv = x @ Wqkv + bqkv -> bf16 Q,K [b,h,t,d], Vt [b,h,d,t]
    gemm_qkv_kernel<<<dim3(3 * D_ / 64, (B_ * T_) / 64), 256, 0, stream>>>(
        x, Wqkv, bqkv, Qg, Kg, Vtg);

    // 2) MFMA flash causal attention -> y fp32 [4096,1024]
    attn_mfma<<<dim3(T_ / 64, H_, B_), 256, 0, stream>>>(Qg, Kg, Vtg, y);

    // 3) out = y @ Wout + bout
    gemm_bias_kernel<64, 64, 16><<<dim3(D_ / 64, (B_ * T_) / 64), 256, 0, stream>>>(
        y, Wout, bout, out, B_ * T_, D_, D_);
}

// Round 3
// 263.900 us; speedup vs baseline: 10.0511x; 2.5177x over previous
//
#include <hip/hip_runtime.h>
#include <hip/hip_bf16.h>
#include <math.h>

#define B_  2
#define T_  2048
#define D_  1024
#define H_  16
#define HD_ 64
#define LSTR 72   // attention LDS row stride (ushorts)

typedef __attribute__((ext_vector_type(8))) short short8;
typedef __attribute__((ext_vector_type(4))) float f32x4;

__device__ __forceinline__ ushort f2bf(float x) {
    unsigned u = __builtin_bit_cast(unsigned, x);
    return (ushort)((u + 0x7FFFu + ((u >> 16) & 1u)) >> 16);  // RTNE
}

__device__ __forceinline__ void load_lds_16B(const ushort* g, ushort* l) {
    __builtin_amdgcn_global_load_lds(
        (const __attribute__((address_space(1))) unsigned*)g,
        (__attribute__((address_space(3))) unsigned*)l, 16, 0, 0);
}

// ---------------------------------------------------------------------------
// x fp32 -> bf16 (elementwise)
// ---------------------------------------------------------------------------
__global__ __launch_bounds__(256)
void cast_x_kernel(const float* __restrict__ x, ushort* __restrict__ xb, int n4)
{
    int i = blockIdx.x * blockDim.x + threadIdx.x;
    for (; i < n4; i += gridDim.x * blockDim.x) {
        float4 v = ((const float4*)x)[i];
        ushort4 o = { f2bf(v.x), f2bf(v.y), f2bf(v.z), f2bf(v.w) };
        ((ushort4*)xb)[i] = o;
    }
}

// ---------------------------------------------------------------------------
// W[K,M] fp32 -> Wt[M,K] bf16 (64x64 LDS tile transpose)
// ---------------------------------------------------------------------------
__global__ __launch_bounds__(256)
void transpose_cast_w(const float* __restrict__ W, ushort* __restrict__ Wt,
                      int K, int M)
{
    __shared__ ushort Ts[64][65];
    const int m0 = blockIdx.x * 64, k0 = blockIdx.y * 64;
    const int tr = threadIdx.x >> 4;   // 0..15
    const int tc = threadIdx.x & 15;   // 0..15
    #pragma unroll
    for (int it = 0; it < 4; it++) {
        int k = tr + it * 16;
        float4 v = *(const float4*)&W[(size_t)(k0 + k) * M + m0 + tc * 4];
        Ts[tc * 4 + 0][k] = f2bf(v.x);
        Ts[tc * 4 + 1][k] = f2bf(v.y);
        Ts[tc * 4 + 2][k] = f2bf(v.z);
        Ts[tc * 4 + 3][k] = f2bf(v.w);
    }
    __syncthreads();
    const int mr = threadIdx.x >> 2;   // 0..63
    const int c4 = threadIdx.x & 3;    // 0..3
    #pragma unroll
    for (int it = 0; it < 4; it++) {
        int kk = c4 * 16 + it * 4;
        ushort4 o = { Ts[mr][kk], Ts[mr][kk + 1], Ts[mr][kk + 2], Ts[mr][kk + 3] };
        *(ushort4*)&Wt[(size_t)(m0 + mr) * K + k0 + kk] = o;
    }
}

// ---------------------------------------------------------------------------
// bf16 MFMA GEMM: C[N,M] = A[N,K] @ Bt[M,K]^T + bias[M]
// 128x128 tile, BK=64, 256 threads (4 waves 2x2), 16x16x32 MFMA, 4x4 per wave.
// global_load_lds width-16 staging; XOR swizzle (granule ^= row&7) since
// padding is impossible with global_load_lds (wave-uniform base + lane*16).
// MODE 0: fp32 C + bias.  MODE 1: QKV epilogue (bf16 Q,K [b,h,t,d]; Vt [b,h,d,t]).
// ---------------------------------------------------------------------------
template<int MODE>
__global__ __launch_bounds__(256)
void mfma_gemm(const ushort* __restrict__ A, const ushort* __restrict__ Bt,
               const float* __restrict__ bias, float* __restrict__ C,
               ushort* __restrict__ Qg, ushort* __restrict__ Kg,
               ushort* __restrict__ Vtg, int K, int M)
{
    __shared__ __align__(16) ushort lds[16384];   // As 8192 | Bs 8192 shorts
    ushort* Asl = lds;
    ushort* Bsl = lds + 8192;

    const int tid = threadIdx.x;
    const int w  = tid >> 6, L = tid & 63;
    const int lt = L & 15, lq = L >> 4;
    const int wr = w >> 1, wc = w & 1;
    const int m0 = blockIdx.x * 128, n0 = blockIdx.y * 128;
    const int rsub = L >> 3;   // 0..7
    const int pgr  = L & 7;    // phys granule slot

    f32x4 acc[4][4] = {};

    for (int k0 = 0; k0 < K; k0 += 64) {
        __syncthreads();
        #pragma unroll
        for (int j = 0; j < 4; j++) {
            const int row  = (w * 4 + j) * 8 + rsub;   // row&7 == rsub
            const int gran = pgr ^ rsub;               // swizzled logical granule
            load_lds_16B(A  + (size_t)(n0 + row) * K + k0 + gran * 8,
                         &Asl[row * 64 + pgr * 8]);
            load_lds_16B(Bt + (size_t)(m0 + row) * K + k0 + gran * 8,
                         &Bsl[row * 64 + pgr * 8]);
        }
        __syncthreads();

        #pragma unroll
        for (int ks = 0; ks < 2; ks++) {
            short8 af[4], bf[4];
            #pragma unroll
            for (int i = 0; i < 4; i++) {
                const int ra = wr * 64 + i * 16 + lt;
                af[i] = *(const short8*)&Asl[ra * 64 + (((ks * 4 + lq) ^ (ra & 7)) * 8)];
                const int rb = wc * 64 + i * 16 + lt;
                bf[i] = *(const short8*)&Bsl[rb * 64 + (((ks * 4 + lq) ^ (rb & 7)) * 8)];
            }
            #pragma unroll
            for (int i = 0; i < 4; i++)
                #pragma unroll
                for (int j = 0; j < 4; j++)
                    acc[i][j] = __builtin_amdgcn_mfma_f32_16x16x32_bf16(af[i], bf[j], acc[i][j], 0, 0, 0);
        }
    }

    // ---- epilogue ----  C/D layout: col = lane&15, row = (lane>>4)*4 + reg
    if (MODE == 0) {
        #pragma unroll
        for (int j = 0; j < 4; j++) {
            const int m = m0 + wc * 64 + j * 16 + lt;
            const float bv = bias[m];
            #pragma unroll
            for (int i = 0; i < 4; i++) {
                const int n = n0 + wr * 64 + i * 16 + lq * 4;
                #pragma unroll
                for (int r = 0; r < 4; r++)
                    C[(size_t)(n + r) * M + m] = acc[i][j][r] + bv;
            }
        }
    } else {
        const int s = m0 >> 10;   // uniform per block (128 | 1024)
        #pragma unroll
        for (int j = 0; j < 4; j++) {
            const int m = m0 + wc * 64 + j * 16 + lt;
            const float bv = bias[m];
            const int h = (m >> 6) & 15, d = m & 63;
            #pragma unroll
            for (int i = 0; i < 4; i++) {
                const int n = n0 + wr * 64 + i * 16 + lq * 4;
                const int b = n >> 11, t = n & 2047;
                if (s < 2) {
                    ushort* dst = (s == 0 ? Qg : Kg);
                    #pragma unroll
                    for (int r = 0; r < 4; r++)
                        dst[((size_t)(b * H_ + h) * T_ + t + r) * HD_ + d] =
                            f2bf(acc[i][j][r] + bv);
                } else {
                    ushort4 o = { f2bf(acc[i][j][0] + bv), f2bf(acc[i][j][1] + bv),
                                  f2bf(acc[i][j][2] + bv), f2bf(acc[i][j][3] + bv) };
                    *(ushort4*)&Vtg[((size_t)(b * H_ + h) * HD_ + d) * T_ + t] = o;
                }
            }
        }
    }
}

// ---------------------------------------------------------------------------
// MFMA bf16 flash attention (validated round 1); now emits bf16 y.
// ---------------------------------------------------------------------------
__global__ __launch_bounds__(256)
void attn_mfma(const ushort* __restrict__ Qg, const ushort* __restrict__ Kg,
               const ushort* __restrict__ Vtg, ushort* __restrict__ yb)
{
    const int qb = blockIdx.x, h = blockIdx.y, b = blockIdx.z;
    const int tid = threadIdx.x;
    const int w  = tid >> 6;
    const int L  = tid & 63;
    const int lt = L & 15;
    const int lq = L >> 4;

    __shared__ __align__(16) ushort Ks [64 * LSTR];
    __shared__ __align__(16) ushort Vts[64 * LSTR];
    __shared__ __align__(16) ushort Ps [4][16 * LSTR];

    const size_t bh = (size_t)(b * H_ + h);
    const ushort* Qbase  = Qg  + bh * T_ * HD_;
    const ushort* Kbase  = Kg  + bh * T_ * HD_;
    const ushort* Vtbase = Vtg + bh * HD_ * T_;

    short8 qf[2];
    {
        const int row = qb * 64 + w * 16 + lt;
        qf[0] = *(const short8*)(Qbase + (size_t)row * HD_ + lq * 8);
        qf[1] = *(const short8*)(Qbase + (size_t)row * HD_ + 32 + lq * 8);
    }

    f32x4 acc_o[4] = {};
    float m_r[4], l_r[4];
    #pragma unroll
    for (int r = 0; r < 4; r++) { m_r[r] = -3.0e38f; l_r[r] = 0.f; }

    const float cscale = 0.125f * 1.4426950408889634f;
    const int tK = tid >> 3;
    const int cK = tid & 7;

    for (int kb = 0; kb <= qb; kb++) {
        __syncthreads();
        #pragma unroll
        for (int rr = 0; rr < 2; rr++) {
            const int row = tK + 32 * rr;
            *(short8*)&Ks [row * LSTR + cK * 8] =
                *(const short8*)(Kbase + (size_t)(kb * 64 + row) * HD_ + cK * 8);
            *(short8*)&Vts[row * LSTR + cK * 8] =
                *(const short8*)(Vtbase + (size_t)row * T_ + kb * 64 + cK * 8);
        }
        __syncthreads();

        f32x4 s_acc[4];
        #pragma unroll
        for (int nt = 0; nt < 4; nt++) {
            short8 kf0 = *(const short8*)&Ks[(nt * 16 + lt) * LSTR + lq * 8];
            short8 kf1 = *(const short8*)&Ks[(nt * 16 + lt) * LSTR + 32 + lq * 8];
            f32x4 c = {};
            c = __builtin_amdgcn_mfma_f32_16x16x32_bf16(qf[0], kf0, c, 0, 0, 0);
            c = __builtin_amdgcn_mfma_f32_16x16x32_bf16(qf[1], kf1, c, 0, 0, 0);
            s_acc[nt] = c;
        }

        #pragma unroll
        for (int nt = 0; nt < 4; nt++)
            #pragma unroll
            for (int r = 0; r < 4; r++)
                s_acc[nt][r] *= cscale;
        if (kb == qb) {
            #pragma unroll
            for (int nt = 0; nt < 4; nt++)
                #pragma unroll
                for (int r = 0; r < 4; r++)
                    if (nt * 16 + lt > w * 16 + lq * 4 + r) s_acc[nt][r] = -3.0e38f;
        }

        float alpha[4];
        #pragma unroll
        for (int r = 0; r < 4; r++) {
            float v = fmaxf(fmaxf(s_acc[0][r], s_acc[1][r]),
                            fmaxf(s_acc[2][r], s_acc[3][r]));
            #pragma unroll
            for (int off = 1; off < 16; off <<= 1)
                v = fmaxf(v, __shfl_xor(v, off, 64));
            float nm = fmaxf(m_r[r], v);
            alpha[r] = exp2f(m_r[r] - nm);
            float ssum = 0.f;
            #pragma unroll
            for (int nt = 0; nt < 4; nt++) {
                float p = exp2f(s_acc[nt][r] - nm);
                s_acc[nt][r] = p;
                ssum += p;
            }
            #pragma unroll
            for (int off = 1; off < 16; off <<= 1)
                ssum += __shfl_xor(ssum, off, 64);
            l_r[r] = l_r[r] * alpha[r] + ssum;
            m_r[r] = nm;
        }

        #pragma unroll
        for (int dt = 0; dt < 4; dt++)
            #pragma unroll
            for (int r = 0; r < 4; r++)
                acc_o[dt][r] *= alpha[r];

        #pragma unroll
        for (int nt = 0; nt < 4; nt++)
            #pragma unroll
            for (int r = 0; r < 4; r++)
                Ps[w][(lq * 4 + r) * LSTR + nt * 16 + lt] = f2bf(s_acc[nt][r]);

        short8 pf0 = *(const short8*)&Ps[w][lt * LSTR + lq * 8];
        short8 pf1 = *(const short8*)&Ps[w][lt * LSTR + 32 + lq * 8];

        #pragma unroll
        for (int dt = 0; dt < 4; dt++) {
            short8 vf0 = *(const short8*)&Vts[(dt * 16 + lt) * LSTR + lq * 8];
            short8 vf1 = *(const short8*)&Vts[(dt * 16 + lt) * LSTR + 32 + lq * 8];
            acc_o[dt] = __builtin_amdgcn_mfma_f32_16x16x32_bf16(pf0, vf0, acc_o[dt], 0, 0, 0);
            acc_o[dt] = __builtin_amdgcn_mfma_f32_16x16x32_bf16(pf1, vf1, acc_o[dt], 0, 0, 0);
        }
    }

    float inv_l[4];
    #pragma unroll
    for (int r = 0; r < 4; r++) inv_l[r] = 1.0f / l_r[r];

    ushort* ybase = yb + (size_t)(b * T_ + qb * 64 + w * 16) * D_ + h * HD_;
    #pragma unroll
    for (int r = 0; r < 4; r++)
        #pragma unroll
        for (int dt = 0; dt < 4; dt++)
            ybase[(size_t)(lq * 4 + r) * D_ + dt * 16 + lt] = f2bf(acc_o[dt][r] * inv_l[r]);
}

// ---------------------------------------------------------------------------
extern "C" void kernel_launch(void* const* d_in, const int* in_sizes, int n_in,
                              void* d_out, int out_size, void* d_ws, size_t ws_size,
                              hipStream_t stream)
{
    const float* x    = (const float*)d_in[0];
    const float* Wqkv = (const float*)d_in[1];
    const float* bqkv = (const float*)d_in[2];
    const float* Wout = (const float*)d_in[3];
    const float* bout = (const float*)d_in[4];
    float* out = (float*)d_out;

    char* ws = (char*)d_ws;
    const size_t NT = (size_t)B_ * T_;           // 4096
    ushort* xb     = (ushort*)ws;                             // 8 MB
    ushort* Wqkvt  = (ushort*)(ws + NT * D_ * 2);             // 6 MB
    ushort* Woutt  = (ushort*)(ws + NT * D_ * 2 + (size_t)3 * D_ * D_ * 2);   // 2 MB
    char*   p      = ws + NT * D_ * 2 + (size_t)4 * D_ * D_ * 2;
    const size_t qkv_elems = (size_t)B_ * H_ * T_ * HD_;      // 4 Mi
    ushort* Qg  = (ushort*)p;                                  // 8 MB
    ushort* Kg  = (ushort*)(p + qkv_elems * 2);                // 8 MB
    ushort* Vtg = (ushort*)(p + qkv_elems * 4);                // 8 MB
    ushort* yb  = (ushort*)(p + qkv_elems * 6);                // 8 MB

    // prep: bf16 casts + weight transposes
    cast_x_kernel<<<1024, 256, 0, stream>>>(x, xb, (int)(NT * D_ / 4));
    transpose_cast_w<<<dim3(3 * D_ / 64, D_ / 64), 256, 0, stream>>>(Wqkv, Wqkvt, D_, 3 * D_);
    transpose_cast_w<<<dim3(D_ / 64, D_ / 64), 256, 0, stream>>>(Wout, Woutt, D_, D_);

    // 1) QKV GEMM (bf16 MFMA) -> Q,K [b,h,t,d], Vt [b,h,d,t]
    mfma_gemm<1><<<dim3(3 * D_ / 128, NT / 128), 256, 0, stream>>>(
        xb, Wqkvt, bqkv, nullptr, Qg, Kg, Vtg, D_, 3 * D_);

    // 2) flash causal attention -> bf16 y
    attn_mfma<<<dim3(T_ / 64, H_, B_), 256, 0, stream>>>(Qg, Kg, Vtg, yb);

    // 3) out = y @ Wout + bout (bf16 MFMA, fp32 out)
    mfma_gemm<0><<<dim3(D_ / 128, NT / 128), 256, 0, stream>>>(
        yb, Woutt, bout, out, nullptr, nullptr, nullptr, D_, D_);
}

// Round 4
// 214.798 us; speedup vs baseline: 12.3487x; 1.2286x over previous
//
#include <hip/hip_runtime.h>
#include <hip/hip_bf16.h>
#include <math.h>

#define B_  2
#define T_  2048
#define D_  1024
#define H_  16
#define HD_ 64

typedef __attribute__((ext_vector_type(8))) short short8;
typedef __attribute__((ext_vector_type(4))) float f32x4;

__device__ __forceinline__ ushort f2bf(float x) {
    unsigned u = __builtin_bit_cast(unsigned, x);
    return (ushort)((u + 0x7FFFu + ((u >> 16) & 1u)) >> 16);  // RTNE
}

__device__ __forceinline__ void load_lds_16B(const ushort* g, ushort* l) {
    __builtin_amdgcn_global_load_lds(
        (const __attribute__((address_space(1))) unsigned*)g,
        (__attribute__((address_space(3))) unsigned*)l, 16, 0, 0);
}

// ---------------------------------------------------------------------------
// x fp32 -> bf16 (elementwise)
// ---------------------------------------------------------------------------
__global__ __launch_bounds__(256)
void cast_x_kernel(const float* __restrict__ x, ushort* __restrict__ xb, int n4)
{
    int i = blockIdx.x * blockDim.x + threadIdx.x;
    for (; i < n4; i += gridDim.x * blockDim.x) {
        float4 v = ((const float4*)x)[i];
        ushort4 o = { f2bf(v.x), f2bf(v.y), f2bf(v.z), f2bf(v.w) };
        ((ushort4*)xb)[i] = o;
    }
}

// ---------------------------------------------------------------------------
// W[K,M] fp32 -> Wt[M,K] bf16 (64x64 LDS tile transpose)
// ---------------------------------------------------------------------------
__global__ __launch_bounds__(256)
void transpose_cast_w(const float* __restrict__ W, ushort* __restrict__ Wt,
                      int K, int M)
{
    __shared__ ushort Ts[64][65];
    const int m0 = blockIdx.x * 64, k0 = blockIdx.y * 64;
    const int tr = threadIdx.x >> 4;
    const int tc = threadIdx.x & 15;
    #pragma unroll
    for (int it = 0; it < 4; it++) {
        int k = tr + it * 16;
        float4 v = *(const float4*)&W[(size_t)(k0 + k) * M + m0 + tc * 4];
        Ts[tc * 4 + 0][k] = f2bf(v.x);
        Ts[tc * 4 + 1][k] = f2bf(v.y);
        Ts[tc * 4 + 2][k] = f2bf(v.z);
        Ts[tc * 4 + 3][k] = f2bf(v.w);
    }
    __syncthreads();
    const int mr = threadIdx.x >> 2;
    const int c4 = threadIdx.x & 3;
    #pragma unroll
    for (int it = 0; it < 4; it++) {
        int kk = c4 * 16 + it * 4;
        ushort4 o = { Ts[mr][kk], Ts[mr][kk + 1], Ts[mr][kk + 2], Ts[mr][kk + 3] };
        *(ushort4*)&Wt[(size_t)(m0 + mr) * K + k0 + kk] = o;
    }
}

// ---------------------------------------------------------------------------
// bf16 MFMA GEMM: C[N,M] = A[N,K] @ Bt[M,K]^T + bias[M]
// 128x128 tile, BK=64, 256 threads (4 waves 2x2), 16x16x32 MFMA, 4x4 per wave.
// MODE 0: fp32 C + bias.  MODE 1: QKV epilogue (bf16 Q*cscale, K [b,h,t,d];
// Vt [b,h,d,t]) — Q pre-scaled by 0.125*log2(e) so attention skips the mult.
// ---------------------------------------------------------------------------
template<int MODE>
__global__ __launch_bounds__(256)
void mfma_gemm(const ushort* __restrict__ A, const ushort* __restrict__ Bt,
               const float* __restrict__ bias, float* __restrict__ C,
               ushort* __restrict__ Qg, ushort* __restrict__ Kg,
               ushort* __restrict__ Vtg, int K, int M)
{
    __shared__ __align__(16) ushort lds[16384];
    ushort* Asl = lds;
    ushort* Bsl = lds + 8192;

    const int tid = threadIdx.x;
    const int w  = tid >> 6, L = tid & 63;
    const int lt = L & 15, lq = L >> 4;
    const int wr = w >> 1, wc = w & 1;
    const int m0 = blockIdx.x * 128, n0 = blockIdx.y * 128;
    const int rsub = L >> 3;
    const int pgr  = L & 7;

    f32x4 acc[4][4] = {};

    for (int k0 = 0; k0 < K; k0 += 64) {
        __syncthreads();
        #pragma unroll
        for (int j = 0; j < 4; j++) {
            const int row  = (w * 4 + j) * 8 + rsub;
            const int gran = pgr ^ rsub;
            load_lds_16B(A  + (size_t)(n0 + row) * K + k0 + gran * 8,
                         &Asl[row * 64 + pgr * 8]);
            load_lds_16B(Bt + (size_t)(m0 + row) * K + k0 + gran * 8,
                         &Bsl[row * 64 + pgr * 8]);
        }
        __syncthreads();

        #pragma unroll
        for (int ks = 0; ks < 2; ks++) {
            short8 af[4], bf[4];
            #pragma unroll
            for (int i = 0; i < 4; i++) {
                const int ra = wr * 64 + i * 16 + lt;
                af[i] = *(const short8*)&Asl[ra * 64 + (((ks * 4 + lq) ^ (ra & 7)) * 8)];
                const int rb = wc * 64 + i * 16 + lt;
                bf[i] = *(const short8*)&Bsl[rb * 64 + (((ks * 4 + lq) ^ (rb & 7)) * 8)];
            }
            #pragma unroll
            for (int i = 0; i < 4; i++)
                #pragma unroll
                for (int j = 0; j < 4; j++)
                    acc[i][j] = __builtin_amdgcn_mfma_f32_16x16x32_bf16(af[i], bf[j], acc[i][j], 0, 0, 0);
        }
    }

    if (MODE == 0) {
        #pragma unroll
        for (int j = 0; j < 4; j++) {
            const int m = m0 + wc * 64 + j * 16 + lt;
            const float bv = bias[m];
            #pragma unroll
            for (int i = 0; i < 4; i++) {
                const int n = n0 + wr * 64 + i * 16 + lq * 4;
                #pragma unroll
                for (int r = 0; r < 4; r++)
                    C[(size_t)(n + r) * M + m] = acc[i][j][r] + bv;
            }
        }
    } else {
        const int s = m0 >> 10;
        const float qs = (s == 0) ? 0.18033688011112042f : 1.0f;  // 0.125*log2(e)
        #pragma unroll
        for (int j = 0; j < 4; j++) {
            const int m = m0 + wc * 64 + j * 16 + lt;
            const float bv = bias[m];
            const int h = (m >> 6) & 15, d = m & 63;
            #pragma unroll
            for (int i = 0; i < 4; i++) {
                const int n = n0 + wr * 64 + i * 16 + lq * 4;
                const int b = n >> 11, t = n & 2047;
                if (s < 2) {
                    ushort* dst = (s == 0 ? Qg : Kg);
                    #pragma unroll
                    for (int r = 0; r < 4; r++)
                        dst[((size_t)(b * H_ + h) * T_ + t + r) * HD_ + d] =
                            f2bf((acc[i][j][r] + bv) * qs);
                } else {
                    ushort4 o = { f2bf(acc[i][j][0] + bv), f2bf(acc[i][j][1] + bv),
                                  f2bf(acc[i][j][2] + bv), f2bf(acc[i][j][3] + bv) };
                    *(ushort4*)&Vtg[((size_t)(b * H_ + h) * HD_ + d) * T_ + t] = o;
                }
            }
        }
    }
}

// ---------------------------------------------------------------------------
// MFMA flash attention v2.
// Block = 4 waves; processes TWO 64-row q-tiles {p, 31-p} -> uniform 17
// kb-iterations per block (kills causal tail). KB=128 keys per iteration.
// K/V staged via global_load_lds w16 with XOR granule swizzle (no padding).
// Q pre-scaled; softmax register-resident (16-lane shfl); P via wave-private
// LDS (C/D-layout -> A-layout round trip).
// ---------------------------------------------------------------------------
__global__ __launch_bounds__(256)
void attn_mfma(const ushort* __restrict__ Qg, const ushort* __restrict__ Kg,
               const ushort* __restrict__ Vtg, ushort* __restrict__ yb)
{
    const int pair = blockIdx.x, h = blockIdx.y, b = blockIdx.z;
    const int tid = threadIdx.x;
    const int w  = tid >> 6, L = tid & 63;
    const int lt = L & 15, lq = L >> 4;

    __shared__ __align__(16) ushort Ks [128 * 64];   // 16 KB
    __shared__ __align__(16) ushort Vts[64 * 128];   // 16 KB
    __shared__ __align__(16) ushort Ps [4][16 * 136]; // 17 KB

    const size_t bh = (size_t)(b * H_ + h);
    const ushort* Qbase  = Qg  + bh * T_ * HD_;
    const ushort* Kbase  = Kg  + bh * T_ * HD_;
    const ushort* Vtbase = Vtg + bh * HD_ * T_;

    const int krow = tid >> 3;   // K staging: row slot (0..31), 8 granules/row
    const int kpg  = tid & 7;
    const int vrow = tid >> 4;   // V staging: d slot (0..15), 16 granules/row
    const int vpg  = tid & 15;

    for (int half = 0; half < 2; half++) {
        const int qb = half ? (31 - pair) : pair;
        const int nk = (qb + 2) >> 1;          // ceil((qb+1)*64 / 128)

        short8 qf0, qf1;
        {
            const int row = qb * 64 + w * 16 + lt;
            qf0 = *(const short8*)(Qbase + (size_t)row * HD_ + lq * 8);
            qf1 = *(const short8*)(Qbase + (size_t)row * HD_ + 32 + lq * 8);
        }

        f32x4 acc_o[4] = {};
        float m_r[4], l_r[4];
        #pragma unroll
        for (int r = 0; r < 4; r++) { m_r[r] = -3.0e38f; l_r[r] = 0.f; }

        for (int kb = 0; kb < nk; kb++) {
            __syncthreads();
            #pragma unroll
            for (int rr = 0; rr < 4; rr++) {
                const int row = krow + 32 * rr;
                const int lg  = kpg ^ (row & 7);
                load_lds_16B(Kbase + (size_t)(kb * 128 + row) * HD_ + lg * 8,
                             &Ks[row * 64 + kpg * 8]);
            }
            #pragma unroll
            for (int rr = 0; rr < 4; rr++) {
                const int d  = vrow + 16 * rr;
                const int lg = vpg ^ (d & 7);
                load_lds_16B(Vtbase + (size_t)d * T_ + kb * 128 + lg * 8,
                             &Vts[d * 128 + vpg * 8]);
            }
            __syncthreads();

            // ---- S = Q K^T : 8 n-tiles x 2 k-steps ----
            f32x4 s[8];
            #pragma unroll
            for (int nt = 0; nt < 8; nt++) {
                const int row = nt * 16 + lt;
                short8 kf0 = *(const short8*)&Ks[row * 64 + ((lq ^ (row & 7)) * 8)];
                short8 kf1 = *(const short8*)&Ks[row * 64 + (((4 + lq) ^ (row & 7)) * 8)];
                f32x4 c = {};
                c = __builtin_amdgcn_mfma_f32_16x16x32_bf16(qf0, kf0, c, 0, 0, 0);
                c = __builtin_amdgcn_mfma_f32_16x16x32_bf16(qf1, kf1, c, 0, 0, 0);
                s[nt] = c;
            }

            if (kb == nk - 1) {   // causal mask, final 128-key block only
                const int gq = qb * 64 + w * 16 + lq * 4;
                #pragma unroll
                for (int nt = 0; nt < 8; nt++) {
                    const int gk = kb * 128 + nt * 16 + lt;
                    #pragma unroll
                    for (int r = 0; r < 4; r++)
                        if (gk > gq + r) s[nt][r] = -3.0e38f;
                }
            }

            // ---- online softmax (base-2, Q pre-scaled) ----
            float alpha[4];
            #pragma unroll
            for (int r = 0; r < 4; r++) {
                float v = s[0][r];
                #pragma unroll
                for (int nt = 1; nt < 8; nt++) v = fmaxf(v, s[nt][r]);
                #pragma unroll
                for (int off = 1; off < 16; off <<= 1)
                    v = fmaxf(v, __shfl_xor(v, off, 64));
                const float nm = fmaxf(m_r[r], v);
                alpha[r] = exp2f(m_r[r] - nm);
                float ssum = 0.f;
                #pragma unroll
                for (int nt = 0; nt < 8; nt++) {
                    float p = exp2f(s[nt][r] - nm);
                    s[nt][r] = p;
                    ssum += p;
                }
                #pragma unroll
                for (int off = 1; off < 16; off <<= 1)
                    ssum += __shfl_xor(ssum, off, 64);
                l_r[r] = l_r[r] * alpha[r] + ssum;
                m_r[r] = nm;
            }

            #pragma unroll
            for (int dt = 0; dt < 4; dt++)
                #pragma unroll
                for (int r = 0; r < 4; r++)
                    acc_o[dt][r] *= alpha[r];

            // ---- P: C/D layout -> wave-private LDS -> A layout ----
            #pragma unroll
            for (int nt = 0; nt < 8; nt++)
                #pragma unroll
                for (int r = 0; r < 4; r++)
                    Ps[w][(lq * 4 + r) * 136 + nt * 16 + lt] = f2bf(s[nt][r]);

            short8 pf[4];
            #pragma unroll
            for (int ks = 0; ks < 4; ks++)
                pf[ks] = *(const short8*)&Ps[w][lt * 136 + ks * 32 + lq * 8];

            // ---- O += P V : 4 d-tiles x 4 k-steps ----
            #pragma unroll
            for (int dt = 0; dt < 4; dt++) {
                const int row = dt * 16 + lt;
                #pragma unroll
                for (int ks = 0; ks < 4; ks++) {
                    short8 vf = *(const short8*)&Vts[row * 128 + (((ks * 4 + lq) ^ (row & 7)) * 8)];
                    acc_o[dt] = __builtin_amdgcn_mfma_f32_16x16x32_bf16(pf[ks], vf, acc_o[dt], 0, 0, 0);
                }
            }
        }

        // ---- epilogue: normalize, bf16 y ----
        float inv_l[4];
        #pragma unroll
        for (int r = 0; r < 4; r++) inv_l[r] = 1.0f / l_r[r];

        ushort* ybase = yb + (size_t)(b * T_ + qb * 64 + w * 16) * D_ + h * HD_;
        #pragma unroll
        for (int r = 0; r < 4; r++)
            #pragma unroll
            for (int dt = 0; dt < 4; dt++)
                ybase[(size_t)(lq * 4 + r) * D_ + dt * 16 + lt] = f2bf(acc_o[dt][r] * inv_l[r]);
    }
}

// ---------------------------------------------------------------------------
extern "C" void kernel_launch(void* const* d_in, const int* in_sizes, int n_in,
                              void* d_out, int out_size, void* d_ws, size_t ws_size,
                              hipStream_t stream)
{
    const float* x    = (const float*)d_in[0];
    const float* Wqkv = (const float*)d_in[1];
    const float* bqkv = (const float*)d_in[2];
    const float* Wout = (const float*)d_in[3];
    const float* bout = (const float*)d_in[4];
    float* out = (float*)d_out;

    char* ws = (char*)d_ws;
    const size_t NT = (size_t)B_ * T_;
    ushort* xb     = (ushort*)ws;
    ushort* Wqkvt  = (ushort*)(ws + NT * D_ * 2);
    ushort* Woutt  = (ushort*)(ws + NT * D_ * 2 + (size_t)3 * D_ * D_ * 2);
    char*   p      = ws + NT * D_ * 2 + (size_t)4 * D_ * D_ * 2;
    const size_t qkv_elems = (size_t)B_ * H_ * T_ * HD_;
    ushort* Qg  = (ushort*)p;
    ushort* Kg  = (ushort*)(p + qkv_elems * 2);
    ushort* Vtg = (ushort*)(p + qkv_elems * 4);
    ushort* yb  = (ushort*)(p + qkv_elems * 6);

    cast_x_kernel<<<1024, 256, 0, stream>>>(x, xb, (int)(NT * D_ / 4));
    transpose_cast_w<<<dim3(3 * D_ / 64, D_ / 64), 256, 0, stream>>>(Wqkv, Wqkvt, D_, 3 * D_);
    transpose_cast_w<<<dim3(D_ / 64, D_ / 64), 256, 0, stream>>>(Wout, Woutt, D_, D_);

    mfma_gemm<1><<<dim3(3 * D_ / 128, NT / 128), 256, 0, stream>>>(
        xb, Wqkvt, bqkv, nullptr, Qg, Kg, Vtg, D_, 3 * D_);

    attn_mfma<<<dim3(16, H_, B_), 256, 0, stream>>>(Qg, Kg, Vtg, yb);

    mfma_gemm<0><<<dim3(D_ / 128, NT / 128), 256, 0, stream>>>(
        yb, Woutt, bout, out, nullptr, nullptr, nullptr, D_, D_);
}